// Round 1
// baseline (964.563 us; speedup 1.0000x reference)
//
#include <hip/hip_runtime.h>
#include <cstdint>
#include <cstddef>

// WindowAttention: B=4096 windows, N=49 tokens, DIM=256, NH=8, HD=32.
// Pipeline: K0 weight transpose->bf16, K1 qkv GEMM (bf16 MFMA), K2 fused
// attention (QK^T + bias + mask + softmax + PV) + output projection.
// Requires ws >= 2*(200704*768 + 768*256 + 256*256) bytes ~= 295 MiB.

#define NTOK 49
#define SCALE 0.17677669529663687f

typedef unsigned short u16;
typedef __attribute__((ext_vector_type(8))) short short8;
typedef __attribute__((ext_vector_type(4))) float f32x4;

__device__ __forceinline__ u16 f2bf(float f) {
    unsigned int u = __float_as_uint(f);
    u = (u + 0x7FFFu + ((u >> 16) & 1u)) >> 16;   // RNE
    return (u16)u;
}

// ---------------- K0: weights -> bf16, transposed to [out_col][k] ----------
__global__ void prep_weights(const float* __restrict__ qkv_w,
                             const float* __restrict__ proj_w,
                             u16* __restrict__ qkv_wT,
                             u16* __restrict__ proj_wT) {
    int i = blockIdx.x * 256 + threadIdx.x;
    if (i < 768 * 256) {
        int oc = i >> 8, k = i & 255;
        qkv_wT[i] = f2bf(qkv_w[k * 768 + oc]);
    }
    int j = i - 768 * 256;
    if (j >= 0 && j < 256 * 256) {
        int oc = j >> 8, k = j & 255;
        proj_wT[j] = f2bf(proj_w[k * 256 + oc]);
    }
}

// ---------------- K1: qkv = x @ qkv_w + b, q pre-scaled, bf16 out ----------
// M=200704 (1568 tiles), N=768 (6 tiles), K=256. 256 thr, 4 waves, 64x64/wave.
__global__ __launch_bounds__(256) void qkv_gemm(
        const float* __restrict__ x, const u16* __restrict__ wT,
        const float* __restrict__ bias, u16* __restrict__ qkv) {
    __shared__ __align__(16) u16 As[128][72];   // +8 pad: bank spread
    __shared__ __align__(16) u16 Bs[128][72];
    const int bid = blockIdx.x;
    const int m0 = (bid / 6) * 128, n0 = (bid % 6) * 128;
    const int t = threadIdx.x;
    const int lane = t & 63, w = t >> 6;
    const int quad = lane >> 4, l16 = lane & 15;
    const int wm = w >> 1, wn = w & 1;
    f32x4 acc[4][4] = {};
    for (int kk = 0; kk < 256; kk += 64) {
        {   // stage A: 128 rows x 64 k, f32 -> bf16
            const int c4 = t & 15, rg = t >> 4;
            #pragma unroll
            for (int i = 0; i < 8; ++i) {
                const int row = rg + i * 16;
                const f32x4 v = *(const f32x4*)(x + (size_t)(m0 + row) * 256 + kk + c4 * 4);
                ushort4 pk;
                pk.x = f2bf(v.x); pk.y = f2bf(v.y); pk.z = f2bf(v.z); pk.w = f2bf(v.w);
                *(ushort4*)&As[row][c4 * 4] = pk;
            }
        }
        {   // stage B: 128 out-cols x 64 k, already bf16
            const int c8 = t & 7, rg = t >> 3;
            #pragma unroll
            for (int i = 0; i < 4; ++i) {
                const int row = rg + i * 32;
                *(uint4*)&Bs[row][c8 * 8] =
                    *(const uint4*)(wT + (size_t)(n0 + row) * 256 + kk + c8 * 8);
            }
        }
        __syncthreads();
        #pragma unroll
        for (int ks = 0; ks < 2; ++ks) {
            short8 af[4], bfr[4];
            #pragma unroll
            for (int i = 0; i < 4; ++i)
                af[i] = *(const short8*)&As[wm * 64 + i * 16 + l16][ks * 32 + quad * 8];
            #pragma unroll
            for (int j = 0; j < 4; ++j)
                bfr[j] = *(const short8*)&Bs[wn * 64 + j * 16 + l16][ks * 32 + quad * 8];
            #pragma unroll
            for (int i = 0; i < 4; ++i)
                #pragma unroll
                for (int j = 0; j < 4; ++j)
                    acc[i][j] = __builtin_amdgcn_mfma_f32_16x16x32_bf16(
                        af[i], bfr[j], acc[i][j], 0, 0, 0);
        }
        __syncthreads();
    }
    // epilogue: + bias, q cols (<256) * SCALE, bf16 store
    #pragma unroll
    for (int j = 0; j < 4; ++j) {
        const int gc = n0 + wn * 64 + j * 16 + l16;
        const float bv = bias[gc];
        const float scl = (gc < 256) ? SCALE : 1.0f;
        #pragma unroll
        for (int i = 0; i < 4; ++i) {
            const int gr = m0 + wm * 64 + i * 16 + quad * 4;
            #pragma unroll
            for (int r = 0; r < 4; ++r)
                qkv[(size_t)(gr + r) * 768 + gc] = f2bf((acc[i][j][r] + bv) * scl);
        }
    }
}

// ---------------- K2: per-window attention + projection --------------------
// 1 block / window, 512 thr = 8 waves = 1 head each.
__global__ __launch_bounds__(512) void attn_proj(
        const u16* __restrict__ qkv, const float* __restrict__ mask,
        const float* __restrict__ rpb, const u16* __restrict__ projT,
        const float* __restrict__ proj_b, float* __restrict__ out) {
    __shared__ __align__(16) u16 QKs[49][520];     // q|k rows, +8 pad
    __shared__ __align__(16) u16 Vt[8][32 * 72];   // V^T per head [d][m], pad 72
    __shared__ __align__(16) u16 Ps[8][16][72];    // P tile C->A layout bounce
    __shared__ __align__(16) u16 OutS[49][264];    // head-concat attn out (bf16)
    const int b = blockIdx.x;
    const int t = threadIdx.x;
    const int lane = t & 63, h = t >> 6;           // wave == head
    const int quad = lane >> 4, l16 = lane & 15;
    const short8 zf = {0, 0, 0, 0, 0, 0, 0, 0};
    const f32x4 zero4 = {0.f, 0.f, 0.f, 0.f};

    // zero Vt so padded k-columns (m=49..63) can never inject NaN into MFMA
    {
        unsigned int* vz = (unsigned int*)&Vt[0][0];
        for (int i = t; i < 8 * 32 * 72 / 2; i += 512) vz[i] = 0;
    }
    __syncthreads();
    const u16* qrow = qkv + (size_t)b * NTOK * 768;
    for (int ch = t; ch < 49 * 64; ch += 512) {    // q|k: 49 x 512 bf16
        const int n = ch >> 6, c8 = ch & 63;
        *(uint4*)&QKs[n][c8 * 8] = *(const uint4*)(qrow + n * 768 + c8 * 8);
    }
    for (int e = t; e < 49 * 256; e += 512) {      // v transposed per head
        const int n = e >> 8, hd = e & 255;
        Vt[hd >> 5][(hd & 31) * 72 + n] = qrow[n * 768 + 512 + hd];
    }
    __syncthreads();

    // ---- S = (Q*scale) K^T : 4x4 tiles of 16x16, K=32 (one MFMA each) ----
    short8 aQ[4], bK[4];
    #pragma unroll
    for (int i = 0; i < 4; ++i) {
        const int r = i * 16 + l16;
        aQ[i] = (r < 49) ? *(const short8*)&QKs[r][h * 32 + quad * 8] : zf;
        bK[i] = (r < 49) ? *(const short8*)&QKs[r][256 + h * 32 + quad * 8] : zf;
    }
    f32x4 S[4][4];
    #pragma unroll
    for (int i = 0; i < 4; ++i)
        #pragma unroll
        for (int j = 0; j < 4; ++j)
            S[i][j] = __builtin_amdgcn_mfma_f32_16x16x32_bf16(aQ[i], bK[j], zero4, 0, 0, 0);

    // ---- + rel-pos bias + mask, row softmax (fp32) ----
    const float* mrow = mask + (size_t)b * (NTOK * NTOK);
    int c7[4], cm[4], cc[4];
    #pragma unroll
    for (int j = 0; j < 4; ++j) {
        cc[j] = j * 16 + l16;
        c7[j] = (cc[j] * 37) >> 8;       // floor(c/7) for c<64
        cm[j] = cc[j] - c7[j] * 7;
    }
    #pragma unroll
    for (int i = 0; i < 4; ++i) {
        #pragma unroll
        for (int r = 0; r < 4; ++r) {
            const int row = i * 16 + quad * 4 + r;   // C-layout row
            const int r7 = (row * 37) >> 8;
            const int rm = row - r7 * 7;
            #pragma unroll
            for (int j = 0; j < 4; ++j) {
                float s = -1e30f;
                if (row < 49 && cc[j] < 49) {
                    const int idx = (r7 - c7[j] + 6) * 13 + (rm - cm[j] + 6);
                    s = S[i][j][r] + rpb[idx * 8 + h] + mrow[row * 49 + cc[j]];
                }
                S[i][j][r] = s;
            }
            float mx = fmaxf(fmaxf(S[i][0][r], S[i][1][r]),
                             fmaxf(S[i][2][r], S[i][3][r]));
            #pragma unroll
            for (int off = 1; off < 16; off <<= 1) mx = fmaxf(mx, __shfl_xor(mx, off));
            float sum = 0.f;
            #pragma unroll
            for (int j = 0; j < 4; ++j) {
                const float e = __expf(S[i][j][r] - mx);
                S[i][j][r] = e;
                sum += e;
            }
            #pragma unroll
            for (int off = 1; off < 16; off <<= 1) sum += __shfl_xor(sum, off);
            const float rinv = 1.0f / sum;
            #pragma unroll
            for (int j = 0; j < 4; ++j) S[i][j][r] = S[i][j][r] * rinv;
        }
    }

    // ---- O = P V : P bounced through LDS (C-layout -> A-layout) ----
    short8 bV[2][2];
    #pragma unroll
    for (int ct = 0; ct < 2; ++ct)
        #pragma unroll
        for (int ks = 0; ks < 2; ++ks)
            bV[ct][ks] = *(const short8*)&Vt[h][(ct * 16 + l16) * 72 + ks * 32 + quad * 8];
    f32x4 O[4][2] = {};
    #pragma unroll
    for (int i = 0; i < 4; ++i) {
        __threadfence_block();   // WAR: prior iter's reads before overwrite
        #pragma unroll
        for (int j = 0; j < 4; ++j)
            #pragma unroll
            for (int r = 0; r < 4; ++r)
                Ps[h][quad * 4 + r][j * 16 + l16] = f2bf(S[i][j][r]);
        __threadfence_block();   // RAW: writes visible before frag reads
        const short8 aP0 = *(const short8*)&Ps[h][l16][quad * 8];
        const short8 aP1 = *(const short8*)&Ps[h][l16][32 + quad * 8];
        #pragma unroll
        for (int ct = 0; ct < 2; ++ct) {
            O[i][ct] = __builtin_amdgcn_mfma_f32_16x16x32_bf16(aP0, bV[ct][0], O[i][ct], 0, 0, 0);
            O[i][ct] = __builtin_amdgcn_mfma_f32_16x16x32_bf16(aP1, bV[ct][1], O[i][ct], 0, 0, 0);
        }
    }
    #pragma unroll
    for (int i = 0; i < 4; ++i)
        #pragma unroll
        for (int ct = 0; ct < 2; ++ct)
            #pragma unroll
            for (int r = 0; r < 4; ++r) {
                const int row = i * 16 + quad * 4 + r;
                if (row < 49) OutS[row][h * 32 + ct * 16 + l16] = f2bf(O[i][ct][r]);
            }
    __syncthreads();

    // ---- proj: [49x256] @ [256x256], wave h -> out cols h*32..h*32+31 ----
    f32x4 P2[4][2] = {};
    #pragma unroll
    for (int ks = 0; ks < 8; ++ks) {
        short8 bW[2];
        #pragma unroll
        for (int ct = 0; ct < 2; ++ct)
            bW[ct] = *(const short8*)(projT + (size_t)(h * 32 + ct * 16 + l16) * 256
                                      + ks * 32 + quad * 8);
        #pragma unroll
        for (int i = 0; i < 4; ++i) {
            const int row = i * 16 + l16;
            const short8 aO = (row < 49) ? *(const short8*)&OutS[row][ks * 32 + quad * 8] : zf;
            #pragma unroll
            for (int ct = 0; ct < 2; ++ct)
                P2[i][ct] = __builtin_amdgcn_mfma_f32_16x16x32_bf16(aO, bW[ct], P2[i][ct], 0, 0, 0);
        }
    }
    #pragma unroll
    for (int ct = 0; ct < 2; ++ct) {
        const int gc = h * 32 + ct * 16 + l16;
        const float pb = proj_b[gc];
        #pragma unroll
        for (int i = 0; i < 4; ++i)
            #pragma unroll
            for (int r = 0; r < 4; ++r) {
                const int row = i * 16 + quad * 4 + r;
                if (row < 49)
                    out[((size_t)b * NTOK + row) * 256 + gc] = P2[i][ct][r] + pb;
            }
    }
}

extern "C" void kernel_launch(void* const* d_in, const int* in_sizes, int n_in,
                              void* d_out, int out_size, void* d_ws, size_t ws_size,
                              hipStream_t stream) {
    const float* x      = (const float*)d_in[0];   // [4096,49,256]
    const float* mask   = (const float*)d_in[1];   // [4096,1,49,49]
    const float* qkv_w  = (const float*)d_in[2];   // [256,768]
    const float* qkv_b  = (const float*)d_in[3];   // [768]
    const float* rpb    = (const float*)d_in[4];   // [169,8]
    const float* proj_w = (const float*)d_in[5];   // [256,256]
    const float* proj_b = (const float*)d_in[6];   // [256]
    float* outp = (float*)d_out;

    u16* qkv     = (u16*)d_ws;                      // 200704*768 bf16
    u16* qkv_wT  = qkv + (size_t)200704 * 768;      // 768*256
    u16* proj_wT = qkv_wT + 768 * 256;              // 256*256

    prep_weights<<<1024, 256, 0, stream>>>(qkv_w, proj_w, qkv_wT, proj_wT);
    qkv_gemm<<<1568 * 6, 256, 0, stream>>>(x, qkv_wT, qkv_b, qkv);
    attn_proj<<<4096, 512, 0, stream>>>(qkv, mask, rpb, proj_wT, proj_b, outp);
}

// Round 2
// 829.997 us; speedup vs baseline: 1.1621x; 1.1621x over previous
//
#include <hip/hip_runtime.h>
#include <cstdint>
#include <cstddef>

// WindowAttention: B=4096 windows, N=49 tokens, DIM=256, NH=8, HD=32.
// K0 weights->bf16T, K1 qkv GEMM (128x256 tile, bf16 MFMA, B via
// global_load_lds), K2 fused attention+projection (2 blocks/CU: Q/K frags
// direct from global, Ps aliased into Vt, per-tile fused softmax+PV).

#define NTOK 49
#define SCALE 0.17677669529663687f

typedef unsigned short u16;
typedef __attribute__((ext_vector_type(8))) short short8;
typedef __attribute__((ext_vector_type(4))) float f32x4;

__device__ __forceinline__ u16 f2bf(float f) {
    unsigned int u = __float_as_uint(f);
    u = (u + 0x7FFFu + ((u >> 16) & 1u)) >> 16;   // RNE
    return (u16)u;
}

__device__ __forceinline__ void async_lds16(void* lds, const void* g) {
    __builtin_amdgcn_global_load_lds(
        (const __attribute__((address_space(1))) void*)g,
        (__attribute__((address_space(3))) void*)lds, 16, 0, 0);
}

// ---------------- K0: weights -> bf16, transposed to [out_col][k] ----------
__global__ void prep_weights(const float* __restrict__ qkv_w,
                             const float* __restrict__ proj_w,
                             u16* __restrict__ qkv_wT,
                             u16* __restrict__ proj_wT) {
    int i = blockIdx.x * 256 + threadIdx.x;
    if (i < 768 * 256) {
        int oc = i >> 8, k = i & 255;
        qkv_wT[i] = f2bf(qkv_w[k * 768 + oc]);
    }
    int j = i - 768 * 256;
    if (j >= 0 && j < 256 * 256) {
        int oc = j >> 8, k = j & 255;
        proj_wT[j] = f2bf(proj_w[k * 256 + oc]);
    }
}

// ---------------- K1: qkv = x @ qkv_w + b, q pre-scaled, bf16 out ----------
// M=200704 (1568 m-tiles of 128), N=768 (3 n-tiles of 256), K=256, BK=64.
// 512 thr = 8 waves (2m x 4n), 64x64 per wave.
__global__ __launch_bounds__(512, 4) void qkv_gemm(
        const float* __restrict__ x, const u16* __restrict__ wT,
        const float* __restrict__ bias, u16* __restrict__ qkv) {
    __shared__ __align__(16) u16 As[128 * 64];   // unpadded (m97 pattern)
    __shared__ __align__(16) u16 Bs[256 * 64];   // unpadded: global_load_lds dest
    const int bid = blockIdx.x;
    const int m0 = (bid % 1568) * 128, n0 = (bid / 1568) * 256;
    const int t = threadIdx.x;
    const int lane = t & 63, w = t >> 6;
    const int quad = lane >> 4, l16 = lane & 15;
    const int wm = w & 1, wn = w >> 1;
    const int ar = t >> 2, ac = (t & 3) * 16;          // A staging: 1 row-quarter
    const int br = t >> 3, bc = (t & 7) * 8;           // B staging row/col (elems)
    f32x4 acc[4][4] = {};
    for (int kk = 0; kk < 256; kk += 64) {
        #pragma unroll
        for (int c = 0; c < 4; ++c)                    // B: 256x64 bf16, async DMA
            async_lds16(&Bs[c * 4096 + t * 8],
                        wT + (size_t)(n0 + c * 64 + br) * 256 + kk + bc);
        {                                               // A: 128x64 f32 -> bf16
            const float* src = x + (size_t)(m0 + ar) * 256 + kk + ac;
            const f32x4 v0 = *(const f32x4*)(src);
            const f32x4 v1 = *(const f32x4*)(src + 4);
            const f32x4 v2 = *(const f32x4*)(src + 8);
            const f32x4 v3 = *(const f32x4*)(src + 12);
            ushort4 p0, p1, p2, p3;
            p0.x=f2bf(v0.x); p0.y=f2bf(v0.y); p0.z=f2bf(v0.z); p0.w=f2bf(v0.w);
            p1.x=f2bf(v1.x); p1.y=f2bf(v1.y); p1.z=f2bf(v1.z); p1.w=f2bf(v1.w);
            p2.x=f2bf(v2.x); p2.y=f2bf(v2.y); p2.z=f2bf(v2.z); p2.w=f2bf(v2.w);
            p3.x=f2bf(v3.x); p3.y=f2bf(v3.y); p3.z=f2bf(v3.z); p3.w=f2bf(v3.w);
            uint4 q0, q1;
            q0.x=*(unsigned*)&p0.x; q0.y=*(unsigned*)&p0.z;
            q0.z=*(unsigned*)&p1.x; q0.w=*(unsigned*)&p1.z;
            q1.x=*(unsigned*)&p2.x; q1.y=*(unsigned*)&p2.z;
            q1.z=*(unsigned*)&p3.x; q1.w=*(unsigned*)&p3.z;
            *(uint4*)&As[ar * 64 + ac] = q0;
            *(uint4*)&As[ar * 64 + ac + 8] = q1;
        }
        __syncthreads();
        #pragma unroll
        for (int ks = 0; ks < 2; ++ks) {
            short8 af[4], bfr[4];
            #pragma unroll
            for (int i = 0; i < 4; ++i)
                af[i] = *(const short8*)&As[(wm * 64 + i * 16 + l16) * 64 + ks * 32 + quad * 8];
            #pragma unroll
            for (int j = 0; j < 4; ++j)
                bfr[j] = *(const short8*)&Bs[(wn * 64 + j * 16 + l16) * 64 + ks * 32 + quad * 8];
            #pragma unroll
            for (int i = 0; i < 4; ++i)
                #pragma unroll
                for (int j = 0; j < 4; ++j)
                    acc[i][j] = __builtin_amdgcn_mfma_f32_16x16x32_bf16(
                        af[i], bfr[j], acc[i][j], 0, 0, 0);
        }
        __syncthreads();
    }
    #pragma unroll
    for (int j = 0; j < 4; ++j) {
        const int gc = n0 + wn * 64 + j * 16 + l16;
        const float bv = bias[gc];
        const float scl = (gc < 256) ? SCALE : 1.0f;
        #pragma unroll
        for (int i = 0; i < 4; ++i) {
            const int gr = m0 + wm * 64 + i * 16 + quad * 4;
            #pragma unroll
            for (int r = 0; r < 4; ++r)
                qkv[(size_t)(gr + r) * 768 + gc] = f2bf((acc[i][j][r] + bv) * scl);
        }
    }
}

// ---------------- K2: per-window attention + projection --------------------
// 1 block / window, 512 thr = 8 waves = 1 head each. 60.7 KB LDS -> 2 blk/CU.
__global__ __launch_bounds__(512, 4) void attn_proj(
        const u16* __restrict__ qkv, const float* __restrict__ mask,
        const float* __restrict__ rpb, const u16* __restrict__ projT,
        const float* __restrict__ proj_b, float* __restrict__ out) {
    __shared__ __align__(16) u16 Vt[8][32 * 68];   // V^T per head [d][m]; rows 0..15 reused as Ps
    __shared__ __align__(16) u16 OutS[49][264];    // head-concat attn out (bf16)
    const int b = blockIdx.x;
    const int t = threadIdx.x;
    const int lane = t & 63, h = t >> 6;           // wave == head
    const int quad = lane >> 4, l16 = lane & 15;
    const short8 zf = {0, 0, 0, 0, 0, 0, 0, 0};
    const f32x4 zero4 = {0.f, 0.f, 0.f, 0.f};

    // zero Vt: padded m-columns (49..63) must be 0.0 for PV MFMA
    {
        unsigned int* vz = (unsigned int*)&Vt[0][0];
        for (int i = t; i < 8 * 32 * 68 / 2; i += 512) vz[i] = 0;
    }
    __syncthreads();
    const u16* qrow = qkv + (size_t)b * NTOK * 768;
    for (int idx = t; idx < NTOK * 64; idx += 512) {   // V^T stage, ushort4 loads
        const int n = idx >> 6, hd = (idx & 63) * 4;
        const ushort4 v = *(const ushort4*)(qrow + n * 768 + 512 + hd);
        u16* vt = &Vt[hd >> 5][0];
        const int d = hd & 31;
        vt[(d + 0) * 68 + n] = v.x;
        vt[(d + 1) * 68 + n] = v.y;
        vt[(d + 2) * 68 + n] = v.z;
        vt[(d + 3) * 68 + n] = v.w;
    }
    __syncthreads();

    // K frags (B operand), direct from global (16 B/lane)
    short8 bK[4];
    #pragma unroll
    for (int j = 0; j < 4; ++j) {
        const int r = j * 16 + l16;
        bK[j] = (r < NTOK) ? *(const short8*)(qrow + r * 768 + 256 + h * 32 + quad * 8) : zf;
    }
    // V frags (B operand for PV), from LDS
    short8 bV[2][2];
    #pragma unroll
    for (int ct = 0; ct < 2; ++ct)
        #pragma unroll
        for (int ks = 0; ks < 2; ++ks)
            bV[ct][ks] = *(const short8*)&Vt[h][(ct * 16 + l16) * 68 + ks * 32 + quad * 8];
    __threadfence_block();   // bV reads drained before Ps writes into same region

    u16* Ps = &Vt[h][0];     // 16 rows, stride 68 (wave-private alias)
    const float* mrow = mask + (size_t)b * (NTOK * NTOK);
    int cc[4], c7[4], cm[4];
    #pragma unroll
    for (int j = 0; j < 4; ++j) {
        cc[j] = j * 16 + l16;
        c7[j] = (cc[j] * 37) >> 8;       // floor(c/7) for c<64
        cm[j] = cc[j] - c7[j] * 7;
    }

    // fused per-16-row-tile: QK^T -> bias+mask+softmax -> PV -> OutS
    #pragma unroll
    for (int i = 0; i < 4; ++i) {
        const int qr = i * 16 + l16;
        const short8 aQ = (qr < NTOK)
            ? *(const short8*)(qrow + qr * 768 + h * 32 + quad * 8) : zf;
        f32x4 S[4];
        #pragma unroll
        for (int j = 0; j < 4; ++j)
            S[j] = __builtin_amdgcn_mfma_f32_16x16x32_bf16(aQ, bK[j], zero4, 0, 0, 0);
        #pragma unroll
        for (int r = 0; r < 4; ++r) {
            const int row = i * 16 + quad * 4 + r;   // C-layout row
            const int r7 = (row * 37) >> 8;
            const int rm = row - r7 * 7;
            #pragma unroll
            for (int j = 0; j < 4; ++j) {
                float s = -1e30f;
                if (row < NTOK && cc[j] < NTOK) {
                    const int idx = (r7 - c7[j] + 6) * 13 + (rm - cm[j] + 6);
                    s = S[j][r] + rpb[idx * 8 + h] + mrow[row * 49 + cc[j]];
                }
                S[j][r] = s;
            }
            float mx = fmaxf(fmaxf(S[0][r], S[1][r]), fmaxf(S[2][r], S[3][r]));
            #pragma unroll
            for (int off = 1; off < 16; off <<= 1) mx = fmaxf(mx, __shfl_xor(mx, off));
            float sum = 0.f;
            #pragma unroll
            for (int j = 0; j < 4; ++j) {
                const float e = __expf(S[j][r] - mx);
                S[j][r] = e;
                sum += e;
            }
            #pragma unroll
            for (int off = 1; off < 16; off <<= 1) sum += __shfl_xor(sum, off);
            const float rinv = 1.0f / sum;
            #pragma unroll
            for (int j = 0; j < 4; ++j) S[j][r] = S[j][r] * rinv;
        }
        __threadfence_block();   // WAR: prior iter's aP reads before overwrite
        #pragma unroll
        for (int j = 0; j < 4; ++j)
            #pragma unroll
            for (int r = 0; r < 4; ++r)
                Ps[(quad * 4 + r) * 68 + j * 16 + l16] = f2bf(S[j][r]);
        __threadfence_block();   // RAW: P writes visible before frag reads
        const short8 aP0 = *(const short8*)&Ps[l16 * 68 + quad * 8];
        const short8 aP1 = *(const short8*)&Ps[l16 * 68 + 32 + quad * 8];
        f32x4 O0 = __builtin_amdgcn_mfma_f32_16x16x32_bf16(aP0, bV[0][0], zero4, 0, 0, 0);
        O0 = __builtin_amdgcn_mfma_f32_16x16x32_bf16(aP1, bV[0][1], O0, 0, 0, 0);
        f32x4 O1 = __builtin_amdgcn_mfma_f32_16x16x32_bf16(aP0, bV[1][0], zero4, 0, 0, 0);
        O1 = __builtin_amdgcn_mfma_f32_16x16x32_bf16(aP1, bV[1][1], O1, 0, 0, 0);
        #pragma unroll
        for (int r = 0; r < 4; ++r) {
            const int row = i * 16 + quad * 4 + r;
            if (row < NTOK) {
                OutS[row][h * 32 + l16] = f2bf(O0[r]);
                OutS[row][h * 32 + 16 + l16] = f2bf(O1[r]);
            }
        }
    }
    __syncthreads();

    // ---- proj: [49x256] @ [256x256], wave h -> out cols h*32..h*32+31 ----
    f32x4 P2[4][2] = {};
    #pragma unroll
    for (int ks = 0; ks < 8; ++ks) {
        short8 bW[2];
        #pragma unroll
        for (int ct = 0; ct < 2; ++ct)
            bW[ct] = *(const short8*)(projT + (size_t)(h * 32 + ct * 16 + l16) * 256
                                      + ks * 32 + quad * 8);
        #pragma unroll
        for (int i = 0; i < 4; ++i) {
            const int row = i * 16 + l16;
            const short8 aO = (row < NTOK) ? *(const short8*)&OutS[row][ks * 32 + quad * 8] : zf;
            #pragma unroll
            for (int ct = 0; ct < 2; ++ct)
                P2[i][ct] = __builtin_amdgcn_mfma_f32_16x16x32_bf16(aO, bW[ct], P2[i][ct], 0, 0, 0);
        }
    }
    #pragma unroll
    for (int ct = 0; ct < 2; ++ct) {
        const int gc = h * 32 + ct * 16 + l16;
        const float pb = proj_b[gc];
        #pragma unroll
        for (int i = 0; i < 4; ++i)
            #pragma unroll
            for (int r = 0; r < 4; ++r) {
                const int row = i * 16 + quad * 4 + r;
                if (row < NTOK)
                    out[((size_t)b * NTOK + row) * 256 + gc] = P2[i][ct][r] + pb;
            }
    }
}

extern "C" void kernel_launch(void* const* d_in, const int* in_sizes, int n_in,
                              void* d_out, int out_size, void* d_ws, size_t ws_size,
                              hipStream_t stream) {
    const float* x      = (const float*)d_in[0];   // [4096,49,256]
    const float* mask   = (const float*)d_in[1];   // [4096,1,49,49]
    const float* qkv_w  = (const float*)d_in[2];   // [256,768]
    const float* qkv_b  = (const float*)d_in[3];   // [768]
    const float* rpb    = (const float*)d_in[4];   // [169,8]
    const float* proj_w = (const float*)d_in[5];   // [256,256]
    const float* proj_b = (const float*)d_in[6];   // [256]
    float* outp = (float*)d_out;

    u16* qkv     = (u16*)d_ws;                      // 200704*768 bf16
    u16* qkv_wT  = qkv + (size_t)200704 * 768;      // 768*256
    u16* proj_wT = qkv_wT + 768 * 256;              // 256*256

    prep_weights<<<1024, 256, 0, stream>>>(qkv_w, proj_w, qkv_wT, proj_wT);
    qkv_gemm<<<1568 * 3, 512, 0, stream>>>(x, qkv_wT, qkv_b, qkv);
    attn_proj<<<4096, 512, 0, stream>>>(qkv, mask, rpb, proj_wT, proj_b, outp);
}